// Round 5
// baseline (103.221 us; speedup 1.0000x reference)
//
#include <hip/hip_runtime.h>
#include <math.h>

// ClipStyleContrastiveLoss on MI355X (gfx950).
// Math reduction (BETA=1 => imp==neg):
//   E = exp(L/t), exp(2L/t) = E^2
//   S1[i] = rowsum(E)[i] + colsum(E)[i] - 2*E[i,i]
//   S2[i] = rowsum(E^2)[i] + colsum(E^2)[i] - 2*E[i,i]^2
//   reweight = N*S2/S1 ; Ng = (reweight - tau*N*pos)/(1-tau), clamped at N*e^{-1/t}
//   loss = mean over B rows of log((pos+Ng+eps)/pos)
//
// R5: R4's pass1 unchanged (best so far). Removed the d_out memset graph node:
// pass2 uses last-block-done (threadfence + ticket atomic) and plain-stores out.
// Ticket zeroed by pass1 (kernel boundary orders it). Graph: 3 nodes -> 2.

#define THREADS    256
// 1/(TEMPERATURE*ln2) = 2/ln2 : exp(x/t) = exp2(x*EXP_SCALE)
#define EXP_SCALE  2.885390081777927f

__global__ __launch_bounds__(THREADS) void pass1_kernel(
    const float* __restrict__ L,
    float2* __restrict__ rowP,   // [4][B]  (E,E2) row sums per col-stripe
    float2* __restrict__ colP,   // [S][B]  (E,E2) col partials, S = B/16
    unsigned int* __restrict__ ticket,
    int B)
{
    __shared__ float ldsE [4][1024];   // 16 KB
    __shared__ float ldsE2[4][1024];   // 16 KB

    const int t       = threadIdx.x;
    const int lane    = t & 63;
    const int wave    = t >> 6;
    const int x       = blockIdx.x;            // col stripe (1024 cols)
    const int s       = blockIdx.y;            // row stripe (16 rows)
    const int row0    = s * 16 + wave * 4;     // wave's 4 rows
    const int colBase = x * 1024 + lane * 4;

    if (x == 0 && s == 0 && t == 0) *ticket = 0u;   // reset for pass2

    float cE[16], cE2[16], rs[4], rs2[4];
#pragma unroll
    for (int k = 0; k < 16; ++k) { cE[k] = 0.f; cE2[k] = 0.f; }

#pragma unroll
    for (int r = 0; r < 4; ++r) {
        const float* Lr = L + (size_t)(row0 + r) * B + colBase;
        float a = 0.f, b = 0.f;
#pragma unroll
        for (int j = 0; j < 4; ++j) {
            const float4 v = *reinterpret_cast<const float4*>(Lr + j * 256);
            float e0 = exp2f(v.x * EXP_SCALE);
            float e1 = exp2f(v.y * EXP_SCALE);
            float e2 = exp2f(v.z * EXP_SCALE);
            float e3 = exp2f(v.w * EXP_SCALE);
            float q0 = e0 * e0, q1 = e1 * e1, q2 = e2 * e2, q3 = e3 * e3;
            cE [j*4+0] += e0; cE [j*4+1] += e1; cE [j*4+2] += e2; cE [j*4+3] += e3;
            cE2[j*4+0] += q0; cE2[j*4+1] += q1; cE2[j*4+2] += q2; cE2[j*4+3] += q3;
            a += (e0 + e1) + (e2 + e3);
            b += (q0 + q1) + (q2 + q3);
        }
        rs[r] = a; rs2[r] = b;
    }

    // Deferred row reductions (out of the load loop — no per-row dep barrier).
#pragma unroll
    for (int r = 0; r < 4; ++r) {
        float a = rs[r], b = rs2[r];
#pragma unroll
        for (int off = 32; off > 0; off >>= 1) {
            a += __shfl_down(a, off, 64);
            b += __shfl_down(b, off, 64);
        }
        if (lane == 0) rowP[(size_t)x * B + row0 + r] = make_float2(a, b);
    }

    // Cross-wave col combine via LDS, then packed float2 stripe store.
#pragma unroll
    for (int j = 0; j < 4; ++j) {
        *reinterpret_cast<float4*>(&ldsE [wave][lane * 4 + j * 256]) =
            make_float4(cE [j*4+0], cE [j*4+1], cE [j*4+2], cE [j*4+3]);
        *reinterpret_cast<float4*>(&ldsE2[wave][lane * 4 + j * 256]) =
            make_float4(cE2[j*4+0], cE2[j*4+1], cE2[j*4+2], cE2[j*4+3]);
    }
    __syncthreads();

#pragma unroll
    for (int m = 0; m < 4; ++m) {
        const int c = t + m * 256;
        float se  = (ldsE [0][c] + ldsE [1][c]) + (ldsE [2][c] + ldsE [3][c]);
        float se2 = (ldsE2[0][c] + ldsE2[1][c]) + (ldsE2[2][c] + ldsE2[3][c]);
        colP[(size_t)s * B + x * 1024 + c] = make_float2(se, se2);   // coalesced 8B
    }
}

// Merge S=256 stripe partials + row sums + diag -> per-block loss partial;
// last block (ticket) reduces the 256 partials and stores out. No atomicAdd on out,
// no pre-zeroed memory needed.
__global__ __launch_bounds__(THREADS) void pass2_kernel(
    const float* __restrict__ L,
    const float2* __restrict__ rowP,
    const float2* __restrict__ colP,
    float* __restrict__ lossPart,        // [gridDim.x]
    unsigned int* __restrict__ ticket,
    float* __restrict__ out,
    int B, int S)
{
    const int t    = threadIdx.x;
    const int c    = t & 15;
    const int g    = t >> 4;
    const int base = blockIdx.x * 16;

    float se = 0.f, se2 = 0.f;
    for (int k = g; k < S; k += 16) {
        const float2 v = colP[(size_t)k * B + base + c];
        se += v.x; se2 += v.y;
    }
    __shared__ float2 part[16][17];
    part[g][c] = make_float2(se, se2);
    __syncthreads();

    float blockLoss = 0.f;
    if (t < 16) {
        float colE = 0.f, colE2 = 0.f;
#pragma unroll
        for (int gg = 0; gg < 16; ++gg) {
            colE  += part[gg][t].x;
            colE2 += part[gg][t].y;
        }
        const int i = base + t;
        float rowE = 0.f, rowE2 = 0.f;
#pragma unroll
        for (int x = 0; x < 4; ++x) {
            const float2 rv = rowP[(size_t)x * B + i];
            rowE += rv.x; rowE2 += rv.y;
        }
        const float Nf = (float)(2 * B - 2);
        float dg = L[(size_t)i * B + i];
        float pe = exp2f(dg * EXP_SCALE);
        float S1 = rowE  + colE  - 2.f * pe;
        float S2 = rowE2 + colE2 - 2.f * (pe * pe);
        float rw = Nf * (S2 / S1);                        // N * sum(neg^2)/sum(neg)
        float Ng = (rw - 0.1f * Nf * pe) * (1.f / 0.9f);  // (-tau*N*pos + rw)/(1-tau)
        Ng = fmaxf(Ng, Nf * 0.13533528323661270f);        // N * e^{-1/t}
        float loss = logf((pe + Ng + 1e-8f) / pe);
        // width-16 shfl stays inside lanes 0..15 — safe under the t<16 guard
#pragma unroll
        for (int off = 8; off > 0; off >>= 1) loss += __shfl_down(loss, off, 16);
        blockLoss = loss;
    }

    // Last-block-done final reduction (rocPRIM pattern).
    __shared__ bool isLast;
    if (t == 0) {
        lossPart[blockIdx.x] = blockLoss;
        __threadfence();                                  // release partial
        unsigned int old = atomicAdd(ticket, 1u);         // device-scope
        isLast = (old == (unsigned int)(gridDim.x - 1));
    }
    __syncthreads();

    if (isLast) {
        __threadfence();                                  // acquire partials
        float v = lossPart[t];                            // gridDim.x == THREADS == 256
#pragma unroll
        for (int off = 32; off > 0; off >>= 1) v += __shfl_down(v, off, 64);
        __shared__ float wsum[4];
        const int wave = t >> 6;
        const int lane = t & 63;
        if (lane == 0) wsum[wave] = v;
        __syncthreads();
        if (t == 0) out[0] = ((wsum[0] + wsum[1]) + (wsum[2] + wsum[3])) / (float)B;
    }
}

extern "C" void kernel_launch(void* const* d_in, const int* in_sizes, int n_in,
                              void* d_out, int out_size, void* d_ws, size_t ws_size,
                              hipStream_t stream) {
    const float* L = (const float*)d_in[0];
    int B = 1;
    while ((long long)B * B < (long long)in_sizes[0]) B <<= 1;  // B = 4096
    const int S = B / 16;                                       // 256 row stripes

    float* base = (float*)d_ws;
    unsigned int* ticket = (unsigned int*)base;                 // 1 uint
    float* lossPart = base + 8;                                 // 256 floats
    float2* rowP = (float2*)(base + 8 + 256);                   // 4*B float2 (128 KB)
    float2* colP = rowP + (size_t)4 * B;                        // S*B float2 (8.4 MB)

    dim3 grid1(4, B / 16);                                      // (4, 256) = 1024 blocks
    pass1_kernel<<<grid1, THREADS, 0, stream>>>(L, rowP, colP, ticket, B);
    pass2_kernel<<<B / 16, THREADS, 0, stream>>>(L, rowP, colP, lossPart, ticket,
                                                 (float*)d_out, B, S);
}

// Round 6
// 102.764 us; speedup vs baseline: 1.0044x; 1.0044x over previous
//
#include <hip/hip_runtime.h>
#include <math.h>

// ClipStyleContrastiveLoss on MI355X (gfx950).
// Math reduction (BETA=1 => imp==neg):
//   E = exp(L/t), exp(2L/t) = E^2
//   S1[i] = rowsum(E)[i] + colsum(E)[i] - 2*E[i,i]
//   S2[i] = rowsum(E^2)[i] + colsum(E^2)[i] - 2*E[i,i]^2
//   reweight = N*S2/S1 ; Ng = (reweight - tau*N*pos)/(1-tau), clamped at N*e^{-1/t}
//   loss = mean over B rows of log((pos+Ng+eps)/pos)
//
// R6: R4/R5 structure with grid (8,256) = 2048 blocks, 512-col stripes.
// LDS 32->16 KB (8 blocks/CU), cE/cE2 32->16 VGPRs, 2x waves for latency hiding.
// Partial volume unchanged (8.4 MB). Two graph nodes (no memset; ticket pattern).

#define THREADS    256
// 1/(TEMPERATURE*ln2) = 2/ln2 : exp(x/t) = exp2(x*EXP_SCALE)
#define EXP_SCALE  2.885390081777927f

__global__ __launch_bounds__(THREADS) void pass1_kernel(
    const float* __restrict__ L,
    float2* __restrict__ rowP,   // [8][B]  (E,E2) row sums per col-stripe
    float2* __restrict__ colP,   // [S][B]  (E,E2) col partials, S = B/16
    unsigned int* __restrict__ ticket,
    int B)
{
    __shared__ float ldsE [4][512];   // 8 KB
    __shared__ float ldsE2[4][512];   // 8 KB

    const int t       = threadIdx.x;
    const int lane    = t & 63;
    const int wave    = t >> 6;
    const int x       = blockIdx.x;            // col stripe (512 cols), 0..7
    const int s       = blockIdx.y;            // row stripe (16 rows), 0..255
    const int row0    = s * 16 + wave * 4;     // wave's 4 rows
    const int colBase = x * 512 + lane * 4;

    if (x == 0 && s == 0 && t == 0) *ticket = 0u;   // reset for pass2

    float cE[8], cE2[8], rs[4], rs2[4];
#pragma unroll
    for (int k = 0; k < 8; ++k) { cE[k] = 0.f; cE2[k] = 0.f; }

#pragma unroll
    for (int r = 0; r < 4; ++r) {
        const float* Lr = L + (size_t)(row0 + r) * B + colBase;
        float a = 0.f, b = 0.f;
#pragma unroll
        for (int j = 0; j < 2; ++j) {
            const float4 v = *reinterpret_cast<const float4*>(Lr + j * 256);
            float e0 = exp2f(v.x * EXP_SCALE);
            float e1 = exp2f(v.y * EXP_SCALE);
            float e2 = exp2f(v.z * EXP_SCALE);
            float e3 = exp2f(v.w * EXP_SCALE);
            float q0 = e0 * e0, q1 = e1 * e1, q2 = e2 * e2, q3 = e3 * e3;
            cE [j*4+0] += e0; cE [j*4+1] += e1; cE [j*4+2] += e2; cE [j*4+3] += e3;
            cE2[j*4+0] += q0; cE2[j*4+1] += q1; cE2[j*4+2] += q2; cE2[j*4+3] += q3;
            a += (e0 + e1) + (e2 + e3);
            b += (q0 + q1) + (q2 + q3);
        }
        rs[r] = a; rs2[r] = b;
    }

    // Deferred row reductions (out of the load loop).
#pragma unroll
    for (int r = 0; r < 4; ++r) {
        float a = rs[r], b = rs2[r];
#pragma unroll
        for (int off = 32; off > 0; off >>= 1) {
            a += __shfl_down(a, off, 64);
            b += __shfl_down(b, off, 64);
        }
        if (lane == 0) rowP[(size_t)x * B + row0 + r] = make_float2(a, b);
    }

    // Cross-wave col combine via LDS, then packed float2 stripe store.
#pragma unroll
    for (int j = 0; j < 2; ++j) {
        *reinterpret_cast<float4*>(&ldsE [wave][lane * 4 + j * 256]) =
            make_float4(cE [j*4+0], cE [j*4+1], cE [j*4+2], cE [j*4+3]);
        *reinterpret_cast<float4*>(&ldsE2[wave][lane * 4 + j * 256]) =
            make_float4(cE2[j*4+0], cE2[j*4+1], cE2[j*4+2], cE2[j*4+3]);
    }
    __syncthreads();

    {
        const int c = t & 511;                 // two threads per col? no: 256 threads, 512 cols
    }
#pragma unroll
    for (int m = 0; m < 2; ++m) {
        const int c = t + m * 256;
        float se  = (ldsE [0][c] + ldsE [1][c]) + (ldsE [2][c] + ldsE [3][c]);
        float se2 = (ldsE2[0][c] + ldsE2[1][c]) + (ldsE2[2][c] + ldsE2[3][c]);
        colP[(size_t)s * B + x * 512 + c] = make_float2(se, se2);   // coalesced 8B
    }
}

// Merge S=256 stripe partials + row sums + diag -> per-block loss partial;
// last block (ticket) reduces the 256 partials and stores out.
__global__ __launch_bounds__(THREADS) void pass2_kernel(
    const float* __restrict__ L,
    const float2* __restrict__ rowP,
    const float2* __restrict__ colP,
    float* __restrict__ lossPart,        // [gridDim.x]
    unsigned int* __restrict__ ticket,
    float* __restrict__ out,
    int B, int S)
{
    const int t    = threadIdx.x;
    const int c    = t & 15;
    const int g    = t >> 4;
    const int base = blockIdx.x * 16;

    float se = 0.f, se2 = 0.f;
    for (int k = g; k < S; k += 16) {
        const float2 v = colP[(size_t)k * B + base + c];
        se += v.x; se2 += v.y;
    }
    __shared__ float2 part[16][17];
    part[g][c] = make_float2(se, se2);
    __syncthreads();

    float blockLoss = 0.f;
    if (t < 16) {
        float colE = 0.f, colE2 = 0.f;
#pragma unroll
        for (int gg = 0; gg < 16; ++gg) {
            colE  += part[gg][t].x;
            colE2 += part[gg][t].y;
        }
        const int i = base + t;
        float rowE = 0.f, rowE2 = 0.f;
#pragma unroll
        for (int x = 0; x < 8; ++x) {
            const float2 rv = rowP[(size_t)x * B + i];
            rowE += rv.x; rowE2 += rv.y;
        }
        const float Nf = (float)(2 * B - 2);
        float dg = L[(size_t)i * B + i];
        float pe = exp2f(dg * EXP_SCALE);
        float S1 = rowE  + colE  - 2.f * pe;
        float S2 = rowE2 + colE2 - 2.f * (pe * pe);
        float rw = Nf * (S2 / S1);                        // N * sum(neg^2)/sum(neg)
        float Ng = (rw - 0.1f * Nf * pe) * (1.f / 0.9f);  // (-tau*N*pos + rw)/(1-tau)
        Ng = fmaxf(Ng, Nf * 0.13533528323661270f);        // N * e^{-1/t}
        float loss = logf((pe + Ng + 1e-8f) / pe);
#pragma unroll
        for (int off = 8; off > 0; off >>= 1) loss += __shfl_down(loss, off, 16);
        blockLoss = loss;
    }

    // Last-block-done final reduction.
    __shared__ bool isLast;
    if (t == 0) {
        lossPart[blockIdx.x] = blockLoss;
        __threadfence();
        unsigned int old = atomicAdd(ticket, 1u);
        isLast = (old == (unsigned int)(gridDim.x - 1));
    }
    __syncthreads();

    if (isLast) {
        __threadfence();
        float v = lossPart[t];                            // gridDim.x == 256
#pragma unroll
        for (int off = 32; off > 0; off >>= 1) v += __shfl_down(v, off, 64);
        __shared__ float wsum[4];
        const int wave = t >> 6;
        const int lane = t & 63;
        if (lane == 0) wsum[wave] = v;
        __syncthreads();
        if (t == 0) out[0] = ((wsum[0] + wsum[1]) + (wsum[2] + wsum[3])) / (float)B;
    }
}

extern "C" void kernel_launch(void* const* d_in, const int* in_sizes, int n_in,
                              void* d_out, int out_size, void* d_ws, size_t ws_size,
                              hipStream_t stream) {
    const float* L = (const float*)d_in[0];
    int B = 1;
    while ((long long)B * B < (long long)in_sizes[0]) B <<= 1;  // B = 4096
    const int S = B / 16;                                       // 256 row stripes

    float* base = (float*)d_ws;
    unsigned int* ticket = (unsigned int*)base;                 // 1 uint
    float* lossPart = base + 8;                                 // 256 floats
    float2* rowP = (float2*)(base + 8 + 256);                   // 8*B float2 (256 KB)
    float2* colP = rowP + (size_t)8 * B;                        // S*B float2 (8.4 MB)

    dim3 grid1(8, B / 16);                                      // 2048 blocks, 4 waves each
    pass1_kernel<<<grid1, THREADS, 0, stream>>>(L, rowP, colP, ticket, B);
    pass2_kernel<<<B / 16, THREADS, 0, stream>>>(L, rowP, colP, lossPart, ticket,
                                                 (float*)d_out, B, S);
}